// Round 5
// baseline (384.134 us; speedup 1.0000x reference)
//
#include <hip/hip_runtime.h>

#define NROWS  4194304
#define NBLK   8192                       // (NROWS/2)/256, exact
#define INV_B  (1.0f / 4194304.0f)
#define LOG2E  1.44269504088896340736f
#define LN2    0.69314718055994530942f

// v_exp_f32: 2^x ; v_log_f32: log2(x) — raw builtins avoid glibc name clash.
#define EXP2F(x) __builtin_amdgcn_exp2f(x)
#define LOG2F(x) __builtin_amdgcn_logf(x)

// Fully-inline CE kernel. 2 rows/thread, 512-row/20KB LDS tile per block.
// Lean math: exp2-domain softmax (1 fma + 1 exp per elem), x[t] via one
// ds_read_b32, argmax==3 test as 4 compares (first-occurrence exact:
// a3>=m proves a3 is a max, a3>a0..a2 proves no earlier max).
__global__ __launch_bounds__(256) void ce_main(
        const float4* __restrict__ x4,
        const int2*   __restrict__ tgt2,
        float* __restrict__ ws_sum,
        unsigned int* __restrict__ ws_flag) {
    __shared__ float lds[5120];           // 512 rows x 10 floats
    float4* lds4 = (float4*)lds;

    const int tid = threadIdx.x;
    const int2 t = tgt2[(size_t)blockIdx.x * 256 + tid];   // issue early

    const size_t base4 = (size_t)blockIdx.x * 1280;
#pragma unroll
    for (int k = 0; k < 5; ++k)
        lds4[k * 256 + tid] = x4[base4 + k * 256 + tid];
    __syncthreads();

    // rows 2*tid (lds[20t..20t+9]) and 2*tid+1 (lds[20t+10..20t+19])
    const float4* row = (const float4*)(lds + 20 * tid);
    const float4 f0 = row[0], f1 = row[1], f2 = row[2], f3 = row[3], f4 = row[4];
    const float xt0 = lds[20 * tid + t.x];
    const float xt1 = lds[20 * tid + 10 + t.y];

    // row0: a0..a9 = f0.xyzw f1.xyzw f2.xy   (elem3 = f0.w)
    // row1: a0..a9 = f2.zw f3.xyzw f4.xyzw   (elem3 = f3.y)
    const float m0 = fmaxf(fmaxf(fmaxf(fmaxf(f0.x, f0.y), fmaxf(f0.z, f0.w)),
                                 fmaxf(fmaxf(f1.x, f1.y), fmaxf(f1.z, f1.w))),
                           fmaxf(f2.x, f2.y));
    const float m1 = fmaxf(fmaxf(fmaxf(fmaxf(f2.z, f2.w), fmaxf(f3.x, f3.y)),
                                 fmaxf(fmaxf(f3.z, f3.w), fmaxf(f4.x, f4.y))),
                           fmaxf(f4.z, f4.w));

    const float c0 = -m0 * LOG2E;
    float s0;
    s0  = EXP2F(__builtin_fmaf(f0.x, LOG2E, c0));
    s0 += EXP2F(__builtin_fmaf(f0.y, LOG2E, c0));
    s0 += EXP2F(__builtin_fmaf(f0.z, LOG2E, c0));
    s0 += EXP2F(__builtin_fmaf(f0.w, LOG2E, c0));
    s0 += EXP2F(__builtin_fmaf(f1.x, LOG2E, c0));
    s0 += EXP2F(__builtin_fmaf(f1.y, LOG2E, c0));
    s0 += EXP2F(__builtin_fmaf(f1.z, LOG2E, c0));
    s0 += EXP2F(__builtin_fmaf(f1.w, LOG2E, c0));
    s0 += EXP2F(__builtin_fmaf(f2.x, LOG2E, c0));
    s0 += EXP2F(__builtin_fmaf(f2.y, LOG2E, c0));

    const float c1 = -m1 * LOG2E;
    float s1;
    s1  = EXP2F(__builtin_fmaf(f2.z, LOG2E, c1));
    s1 += EXP2F(__builtin_fmaf(f2.w, LOG2E, c1));
    s1 += EXP2F(__builtin_fmaf(f3.x, LOG2E, c1));
    s1 += EXP2F(__builtin_fmaf(f3.y, LOG2E, c1));
    s1 += EXP2F(__builtin_fmaf(f3.z, LOG2E, c1));
    s1 += EXP2F(__builtin_fmaf(f3.w, LOG2E, c1));
    s1 += EXP2F(__builtin_fmaf(f4.x, LOG2E, c1));
    s1 += EXP2F(__builtin_fmaf(f4.y, LOG2E, c1));
    s1 += EXP2F(__builtin_fmaf(f4.z, LOG2E, c1));
    s1 += EXP2F(__builtin_fmaf(f4.w, LOG2E, c1));

    const float nll0 = __builtin_fmaf(LOG2F(s0), LN2, m0 - xt0);
    const float nll1 = __builtin_fmaf(LOG2F(s1), LN2, m1 - xt1);

    const bool a3_0 = (f0.w >= m0) & (f0.w > f0.x) & (f0.w > f0.y) & (f0.w > f0.z);
    const bool a3_1 = (f3.y >= m1) & (f3.y > f2.z) & (f3.y > f2.w) & (f3.y > f3.x);

    float sum = nll0 + nll1;
    int flag = ((t.x == 2) & (int)a3_0) | ((t.y == 2) & (int)a3_1);

#pragma unroll
    for (int off = 32; off > 0; off >>= 1) sum += __shfl_down(sum, off);
    flag = __any(flag) ? 1 : 0;

    __shared__ float wsum[4];
    __shared__ int   wflag[4];
    const int lane = tid & 63;
    const int wid  = tid >> 6;
    if (lane == 0) { wsum[wid] = sum; wflag[wid] = flag; }
    __syncthreads();
    if (tid == 0) {
        atomicAdd(ws_sum, wsum[0] + wsum[1] + wsum[2] + wsum[3]);
        if (wflag[0] | wflag[1] | wflag[2] | wflag[3]) atomicOr(ws_flag, 1u);
    }
}

__global__ void finalize_kernel(const float* __restrict__ ws_sum,
                                const unsigned int* __restrict__ ws_flag,
                                const int* __restrict__ epoch,
                                float* __restrict__ out) {
    // 64 * epoch^-0.65 + 0.01 ; epoch>0. pow via exp2/log2.
    const float e = (float)epoch[0];
    const float corr = 64.0f * EXP2F(-0.65f * LOG2F(e)) + 0.01f;
    out[0] = ws_sum[0] * INV_B + (ws_flag[0] ? corr : 0.0f);
}

extern "C" void kernel_launch(void* const* d_in, const int* in_sizes, int n_in,
                              void* d_out, int out_size, void* d_ws, size_t ws_size,
                              hipStream_t stream) {
    const float4* x4   = (const float4*)d_in[0];  // logits fp32 [B,10]
    const int2*   tgt2 = (const int2*)  d_in[1];  // targets int32 [B]
    const int*    ep   = (const int*)   d_in[2];  // epoch scalar
    float* out = (float*)d_out;

    float*        ws_sum  = (float*)d_ws;
    unsigned int* ws_flag = (unsigned int*)d_ws + 1;

    hipMemsetAsync(d_ws, 0, 8, stream);   // zero accumulator + flag (ws poisoned 0xAA)
    ce_main<<<NBLK, 256, 0, stream>>>(x4, tgt2, ws_sum, ws_flag);
    finalize_kernel<<<1, 1, 0, stream>>>(ws_sum, ws_flag, ep, out);
}

// Round 6
// 247.776 us; speedup vs baseline: 1.5503x; 1.5503x over previous
//
#include <hip/hip_runtime.h>

#define NROWS  4194304
#define NBLK   8192                       // (NROWS/2)/256, exact
#define INV_B  (1.0f / 4194304.0f)
#define LOG2E  1.44269504088896340736f
#define LN2    0.69314718055994530942f

// v_exp_f32: 2^x ; v_log_f32: log2(x) — raw builtins avoid glibc name clash.
#define EXP2F(x) __builtin_amdgcn_exp2f(x)
#define LOG2F(x) __builtin_amdgcn_logf(x)

// Lean CE kernel. 2 rows/thread, 512-row/20KB LDS tile per block.
// exp2-domain softmax (1 fma + 1 exp per elem), x[t] via one ds_read_b32,
// argmax==3 as 4 compares (first-occurrence exact).
// Reduction: per-block partial STORES (NOT same-address atomics — R0/R4 both
// showed 8192 single-address atomicAdds serialize to a 207us dispatch floor).
__global__ __launch_bounds__(256) void ce_main(
        const float4* __restrict__ x4,
        const int2*   __restrict__ tgt2,
        float* __restrict__ partial,      // [NBLK]
        int*   __restrict__ flags) {      // [NBLK]
    __shared__ float lds[5120];           // 512 rows x 10 floats
    float4* lds4 = (float4*)lds;

    const int tid = threadIdx.x;
    const int2 t = tgt2[(size_t)blockIdx.x * 256 + tid];   // issue early

    const size_t base4 = (size_t)blockIdx.x * 1280;
#pragma unroll
    for (int k = 0; k < 5; ++k)
        lds4[k * 256 + tid] = x4[base4 + k * 256 + tid];
    __syncthreads();

    // rows 2*tid (lds[20t..20t+9]) and 2*tid+1 (lds[20t+10..20t+19])
    const float4* row = (const float4*)(lds + 20 * tid);
    const float4 f0 = row[0], f1 = row[1], f2 = row[2], f3 = row[3], f4 = row[4];
    const float xt0 = lds[20 * tid + t.x];
    const float xt1 = lds[20 * tid + 10 + t.y];

    // row0: a0..a9 = f0.xyzw f1.xyzw f2.xy   (elem3 = f0.w)
    // row1: a0..a9 = f2.zw f3.xyzw f4.xyzw   (elem3 = f3.y)
    const float m0 = fmaxf(fmaxf(fmaxf(fmaxf(f0.x, f0.y), fmaxf(f0.z, f0.w)),
                                 fmaxf(fmaxf(f1.x, f1.y), fmaxf(f1.z, f1.w))),
                           fmaxf(f2.x, f2.y));
    const float m1 = fmaxf(fmaxf(fmaxf(fmaxf(f2.z, f2.w), fmaxf(f3.x, f3.y)),
                                 fmaxf(fmaxf(f3.z, f3.w), fmaxf(f4.x, f4.y))),
                           fmaxf(f4.z, f4.w));

    const float c0 = -m0 * LOG2E;
    float s0;
    s0  = EXP2F(__builtin_fmaf(f0.x, LOG2E, c0));
    s0 += EXP2F(__builtin_fmaf(f0.y, LOG2E, c0));
    s0 += EXP2F(__builtin_fmaf(f0.z, LOG2E, c0));
    s0 += EXP2F(__builtin_fmaf(f0.w, LOG2E, c0));
    s0 += EXP2F(__builtin_fmaf(f1.x, LOG2E, c0));
    s0 += EXP2F(__builtin_fmaf(f1.y, LOG2E, c0));
    s0 += EXP2F(__builtin_fmaf(f1.z, LOG2E, c0));
    s0 += EXP2F(__builtin_fmaf(f1.w, LOG2E, c0));
    s0 += EXP2F(__builtin_fmaf(f2.x, LOG2E, c0));
    s0 += EXP2F(__builtin_fmaf(f2.y, LOG2E, c0));

    const float c1 = -m1 * LOG2E;
    float s1;
    s1  = EXP2F(__builtin_fmaf(f2.z, LOG2E, c1));
    s1 += EXP2F(__builtin_fmaf(f2.w, LOG2E, c1));
    s1 += EXP2F(__builtin_fmaf(f3.x, LOG2E, c1));
    s1 += EXP2F(__builtin_fmaf(f3.y, LOG2E, c1));
    s1 += EXP2F(__builtin_fmaf(f3.z, LOG2E, c1));
    s1 += EXP2F(__builtin_fmaf(f3.w, LOG2E, c1));
    s1 += EXP2F(__builtin_fmaf(f4.x, LOG2E, c1));
    s1 += EXP2F(__builtin_fmaf(f4.y, LOG2E, c1));
    s1 += EXP2F(__builtin_fmaf(f4.z, LOG2E, c1));
    s1 += EXP2F(__builtin_fmaf(f4.w, LOG2E, c1));

    const float nll0 = __builtin_fmaf(LOG2F(s0), LN2, m0 - xt0);
    const float nll1 = __builtin_fmaf(LOG2F(s1), LN2, m1 - xt1);

    const bool a3_0 = (f0.w >= m0) & (f0.w > f0.x) & (f0.w > f0.y) & (f0.w > f0.z);
    const bool a3_1 = (f3.y >= m1) & (f3.y > f2.z) & (f3.y > f2.w) & (f3.y > f3.x);

    float sum = nll0 + nll1;
    int flag = ((t.x == 2) & (int)a3_0) | ((t.y == 2) & (int)a3_1);

#pragma unroll
    for (int off = 32; off > 0; off >>= 1) sum += __shfl_down(sum, off);
    flag = __any(flag) ? 1 : 0;

    __shared__ float wsum[4];
    __shared__ int   wflag[4];
    const int lane = tid & 63;
    const int wid  = tid >> 6;
    if (lane == 0) { wsum[wid] = sum; wflag[wid] = flag; }
    __syncthreads();
    if (tid == 0) {
        partial[blockIdx.x] = wsum[0] + wsum[1] + wsum[2] + wsum[3];
        flags[blockIdx.x]   = wflag[0] | wflag[1] | wflag[2] | wflag[3];
    }
}

__global__ __launch_bounds__(256) void reduce_kernel(
        const float* __restrict__ partial,
        const int*   __restrict__ flags,
        const int*   __restrict__ epoch,
        float* __restrict__ out) {
    float s = 0.0f;
    int f = 0;
    for (int i = threadIdx.x; i < NBLK; i += 256) {
        s += partial[i];
        f |= flags[i];
    }
#pragma unroll
    for (int off = 32; off > 0; off >>= 1) {
        s += __shfl_down(s, off);
        f |= __shfl_down(f, off);
    }
    __shared__ float wsum[4];
    __shared__ int   wflag[4];
    const int lane = threadIdx.x & 63;
    const int wid  = threadIdx.x >> 6;
    if (lane == 0) { wsum[wid] = s; wflag[wid] = f; }
    __syncthreads();
    if (threadIdx.x == 0) {
        const float tot = wsum[0] + wsum[1] + wsum[2] + wsum[3];
        const int ff    = wflag[0] | wflag[1] | wflag[2] | wflag[3];
        const float e   = (float)epoch[0];
        const float corr = 64.0f * EXP2F(-0.65f * LOG2F(e)) + 0.01f;  // 64*e^-0.65
        out[0] = tot * INV_B + (ff ? corr : 0.0f);
    }
}

extern "C" void kernel_launch(void* const* d_in, const int* in_sizes, int n_in,
                              void* d_out, int out_size, void* d_ws, size_t ws_size,
                              hipStream_t stream) {
    const float4* x4   = (const float4*)d_in[0];  // logits fp32 [B,10]
    const int2*   tgt2 = (const int2*)  d_in[1];  // targets int32 [B]
    const int*    ep   = (const int*)   d_in[2];  // epoch scalar
    float* out = (float*)d_out;

    float* partial = (float*)d_ws;            // NBLK floats
    int*   flags   = (int*)d_ws + NBLK;       // NBLK ints (64 KB total, fully
                                              // overwritten every launch)

    ce_main<<<NBLK, 256, 0, stream>>>(x4, tgt2, partial, flags);
    reduce_kernel<<<1, 256, 0, stream>>>(partial, flags, ep, out);
}